// Round 8
// baseline (619.219 us; speedup 1.0000x reference)
//
#include <hip/hip_runtime.h>

// VQ nearest-neighbor, two-pass, swapped-operand MFMA (round 8).
//  pass1: mfma(A=codebook_h, B=z_h) -> lane holds 32 candidates for its own
//         z-row in acc regs; in-lane top-2 fold; csq baked into a 33rd k-tile.
//  gather: certify winner with sound margin / exact-rescore visible / flag;
//  rescue: exact fp32 re-scan of flagged rows.
// score(k) = csq[k] - 2*z.c_k = -2*acc (argmin score == argmax acc)

constexpr int Bn = 8192;
constexpr int Kn = 8192;
constexpr int Dn = 512;

using half8  = __attribute__((ext_vector_type(8)))  _Float16;
using f32x16 = __attribute__((ext_vector_type(16))) float;

// workspace layout (bytes), ~27.7MB
#define WS_CSQ  0u
#define WS_ZSQ  (32u*1024u)
#define WS_MAX  (64u*1024u)
#define WS_CNT  (64u*1024u + 64u)
#define WS_WL   (96u*1024u)
#define WS_PART (1u*1024u*1024u)   // float4 partials[8192][64] = 8MB
#define WS_P2   WS_PART            // rescue p2 aliases PART (dead after gather)
#define WS_CIMG (10u*1024u*1024u)  // codebook h image: 64 blk x 33 kt x 4KB
#define WS_ZIMG (19u*1024u*1024u)  // z h image:        32 blk x 33 kt x 8KB

typedef __attribute__((address_space(3))) void       as3_void;
typedef const __attribute__((address_space(1))) void as1_cvoid;

#define MFMA16 __builtin_amdgcn_mfma_f32_32x32x16_f16

// Fragment-contiguous images: tile = blk*33 + kt; 1KB frag per 32-row group;
// chunk16B[kh*32+rr] = row (grp*32+rr), halves k = kt*16 + kh*8 .. +8.
// kt=32 is the extension tile: codebook rows {-csq/2 hi, lo, 0..}, z rows {1,1,0..}.

// ---------------- prep_sums: row sumsq (exact fp32) + cmax -------------------
__global__ __launch_bounds__(256) void prep_sums(const float* __restrict__ Z,
                                                 const float* __restrict__ Cb,
                                                 char* __restrict__ ws) {
  const int w = threadIdx.x >> 6, lane = threadIdx.x & 63;
  const int rid = blockIdx.x * 4 + w;  // 0..16383
  if (blockIdx.x == 0 && threadIdx.x == 0) *(int*)(ws + WS_CNT) = 0;
  const bool isZ = rid < Bn;
  const int r = isZ ? rid : rid - Bn;
  const float* src = (isZ ? Z : Cb) + (size_t)r * Dn + lane * 8;
  const float4 v0 = *reinterpret_cast<const float4*>(src);
  const float4 v1 = *reinterpret_cast<const float4*>(src + 4);
  float ss = v0.x * v0.x + v0.y * v0.y + v0.z * v0.z + v0.w * v0.w +
             v1.x * v1.x + v1.y * v1.y + v1.z * v1.z + v1.w * v1.w;
#pragma unroll
  for (int off = 32; off; off >>= 1) ss += __shfl_xor(ss, off);
  if (lane == 0) {
    if (isZ) ((float*)(ws + WS_ZSQ))[r] = ss;
    else {
      ((float*)(ws + WS_CSQ))[r] = ss;
      atomicMax((int*)(ws + WS_MAX), __float_as_int(ss));  // ss>0: int order == float order
    }
  }
}

// ---------------- prep_img: wave-per-fragment, coalesced 1KB writes ----------
// regular waves: one (blk,grp,kt-octet); lane: ktsel=lane&1, rr=lane>>1 reads
// 64B (16 f32) of row rr at kt -> writes 2x16B into the contiguous 1KB frag.
__global__ __launch_bounds__(256) void prep_img(const float* __restrict__ Z,
                                                const float* __restrict__ Cb,
                                                char* __restrict__ ws) {
  const int w = threadIdx.x >> 6, lane = threadIdx.x & 63;
  const int wid = blockIdx.x * 4 + w;  // 0..2559
  char* CI = ws + WS_CIMG;
  char* ZI = ws + WS_ZIMG;
  if (wid < 2048) {
    const bool isC = wid < 1024;
    const int f = isC ? wid : wid - 1024;
    const int koct = f & 3;
    const int grp = isC ? ((f >> 2) & 3) : ((f >> 2) & 7);
    const int blk = isC ? (f >> 4) : (f >> 5);
    const int rowbase = (isC ? blk * 128 : blk * 256) + grp * 32;
    const float* src = isC ? Cb : Z;
    char* img = isC ? CI : ZI;
    const int fr = isC ? 256 : 512;
    const int ktsel = lane & 1, rr = lane >> 1;
    const float* rowp = src + (size_t)(rowbase + rr) * Dn;
#pragma unroll
    for (int kp = 0; kp < 4; ++kp) {
      const int kt = koct * 8 + kp * 2 + ktsel;
      const float4 v0 = *reinterpret_cast<const float4*>(rowp + kt * 16);
      const float4 v1 = *reinterpret_cast<const float4*>(rowp + kt * 16 + 4);
      const float4 v2 = *reinterpret_cast<const float4*>(rowp + kt * 16 + 8);
      const float4 v3 = *reinterpret_cast<const float4*>(rowp + kt * 16 + 12);
      const float fl[16] = {v0.x, v0.y, v0.z, v0.w, v1.x, v1.y, v1.z, v1.w,
                            v2.x, v2.y, v2.z, v2.w, v3.x, v3.y, v3.z, v3.w};
      _Float16 h[16];
#pragma unroll
      for (int j = 0; j < 16; ++j) h[j] = (_Float16)fl[j];
      const half8 lo8 = {h[0], h[1], h[2], h[3], h[4], h[5], h[6], h[7]};
      const half8 hi8 = {h[8], h[9], h[10], h[11], h[12], h[13], h[14], h[15]};
      char* fb = img + ((size_t)(blk * 33 + kt) * fr + grp * 64) * 16;
      *reinterpret_cast<half8*>(fb + rr * 16) = lo8;          // kh=0 chunk
      *reinterpret_cast<half8*>(fb + 512 + rr * 16) = hi8;    // kh=1 chunk
    }
  } else if (wid < 2304) {  // C ext frags (csq baked)
    const int e = wid - 2048;
    const int grp = e & 3, blk = e >> 2;
    half8 ev = {0, 0, 0, 0, 0, 0, 0, 0};
    if (lane < 32) {
      const float ss = ((const float*)(ws + WS_CSQ))[blk * 128 + grp * 32 + lane];
      const _Float16 hi = (_Float16)(-0.5f * ss);
      ev[0] = hi;
      ev[1] = (_Float16)(-0.5f * ss - (float)hi);
    }
    char* fb = CI + ((size_t)(blk * 33 + 32) * 256 + grp * 64) * 16;
    *reinterpret_cast<half8*>(fb + lane * 16) = ev;
  } else if (wid < 2560) {  // Z ext frags ({1,1})
    const int e = wid - 2304;
    const int grp = e & 7, blk = e >> 3;
    half8 ev = {0, 0, 0, 0, 0, 0, 0, 0};
    if (lane < 32) { ev[0] = (_Float16)1.f; ev[1] = (_Float16)1.f; }
    char* fb = ZI + ((size_t)(blk * 33 + 32) * 512 + grp * 64) * 16;
    *reinterpret_cast<half8*>(fb + lane * 16) = ev;
  }
}

// ---------------- pass1: swapped-operand MFMA + in-lane top-2 ----------------
// 512 blocks, 256 thr (4 waves), 2 blocks/CU. XCD swizzle: xcd = bid&7 hosts
// zblks 4*xcd..+3 x all 16 splits -> z slice 1.1MB L2-resident per XCD.
// Unit = 2 flat k-tiles (132 total, 4 panels x 33); 3 x 16KB LDS bufs,
// prefetch distance 2 units; A (codebook) global->reg, prefetch 1 unit.
__global__ __launch_bounds__(256, 2) void vq_pass1(char* __restrict__ ws) {
  __shared__ uint4 lds4[3072];  // 48KB
  char* lds = (char*)lds4;
  const int t = threadIdx.x, lane = t & 63, w = t >> 6;
  const int wm = w >> 1, wn = w & 1;
  const int bid = blockIdx.x;
  const int zblk = (bid & 7) * 4 + ((bid >> 3) & 3);
  const int split = bid >> 5;
  const int r31 = lane & 31, kh = lane >> 5;
  const char* CI = ws + WS_CIMG;
  const char* ZI = ws + WS_ZIMG;
  const size_t l16 = (size_t)lane * 16;
  const size_t zbase = (size_t)zblk * 33 * 8192 + (size_t)w * 2048 + l16;
  const size_t abase = (size_t)(wm * 2) * 1024 + l16;

  float qs1[4], qs2[4];
  int qi1[4];
#pragma unroll
  for (int nb = 0; nb < 4; ++nb) { qs1[nb] = -3e38f; qs2[nb] = -3e38f; qi1[nb] = 0x7fffffff; }
  f32x16 acc[2][4] = {};

  auto STAGE = [&](int u, int bsel) {  // stage flat kts 2u,2u+1 (z side)
#pragma unroll
    for (int j = 0; j < 2; ++j) {
      const int f = 2 * u + j;
      const int k = f - (f / 33) * 33;
      const char* s = ZI + zbase + (size_t)k * 8192;
      char* d = lds + bsel * 16384 + j * 8192 + w * 2048;
      __builtin_amdgcn_global_load_lds((as1_cvoid*)(s), (as3_void*)(d), 16, 0, 0);
      __builtin_amdgcn_global_load_lds((as1_cvoid*)(s + 1024), (as3_void*)(d + 1024), 16, 0, 0);
    }
  };
  auto LOAD_A = [&](int u, half8 (&a)[4]) {  // codebook frags for flat kts 2u,2u+1
#pragma unroll
    for (int j = 0; j < 2; ++j) {
      const int f = 2 * u + j;
      const int p = f / 33, k = f - p * 33;
      const char* s = CI + (size_t)((split * 4 + p) * 33 + k) * 4096 + abase;
      a[j * 2 + 0] = *reinterpret_cast<const half8*>(s);
      a[j * 2 + 1] = *reinterpret_cast<const half8*>(s + 1024);
    }
  };
  auto FOLD = [&](int p) {  // in-lane top-2 over this panel's 32 candidates
    const int cbase = split * 512 + p * 128 + wm * 64 + 4 * kh;
#pragma unroll
    for (int nb = 0; nb < 4; ++nb) {
      float m1 = qs1[nb], m2 = qs2[nb];
      int i1 = qi1[nb];
#pragma unroll
      for (int ms = 0; ms < 2; ++ms)
#pragma unroll
        for (int r = 0; r < 16; ++r) {
          const float a = acc[ms][nb][r];
          const int ci = cbase + ms * 32 + (r & 3) + 8 * (r >> 2);
          const bool gt = (a > m1) || (a == m1 && ci < i1);
          const float nm2 = gt ? m1 : fmaxf(m2, a);
          m1 = gt ? a : m1;
          i1 = gt ? ci : i1;
          m2 = nm2;
        }
      qs1[nb] = m1; qs2[nb] = m2; qi1[nb] = i1;
    }
#pragma unroll
    for (int ms = 0; ms < 2; ++ms)
#pragma unroll
      for (int nb = 0; nb < 4; ++nb) acc[ms][nb] = (f32x16)0.f;
  };

  half8 aC[4], aN[4];
  // prologue: S(0)->buf0, A(0), S(1)->buf1; wait S(0)+A(0) (S(1) in flight)
  STAGE(0, 0);
  LOAD_A(0, aC);
  STAGE(1, 1);
  asm volatile("s_waitcnt vmcnt(4)" ::: "memory");
  __builtin_amdgcn_s_barrier();

  auto BODY = [&](int u, half8 (&AU)[4], half8 (&AP)[4]) {
    if (u + 1 < 66) LOAD_A(u + 1, AP);           // 4 loads (issued first)
    if (u + 2 < 66) STAGE(u + 2, (u + 2) % 3);   // 4 loads
    const char* B0 = lds + (u % 3) * 16384 + (size_t)wn * 4096 + l16;
    __builtin_amdgcn_s_setprio(1);
#pragma unroll
    for (int j = 0; j < 2; ++j) {
      const char* bb = B0 + j * 8192;
      const half8 b0 = *reinterpret_cast<const half8*>(bb);
      const half8 b1 = *reinterpret_cast<const half8*>(bb + 1024);
      const half8 b2 = *reinterpret_cast<const half8*>(bb + 2048);
      const half8 b3 = *reinterpret_cast<const half8*>(bb + 3072);
      acc[0][0] = MFMA16(AU[j * 2], b0, acc[0][0], 0, 0, 0);
      acc[0][1] = MFMA16(AU[j * 2], b1, acc[0][1], 0, 0, 0);
      acc[0][2] = MFMA16(AU[j * 2], b2, acc[0][2], 0, 0, 0);
      acc[0][3] = MFMA16(AU[j * 2], b3, acc[0][3], 0, 0, 0);
      acc[1][0] = MFMA16(AU[j * 2 + 1], b0, acc[1][0], 0, 0, 0);
      acc[1][1] = MFMA16(AU[j * 2 + 1], b1, acc[1][1], 0, 0, 0);
      acc[1][2] = MFMA16(AU[j * 2 + 1], b2, acc[1][2], 0, 0, 0);
      acc[1][3] = MFMA16(AU[j * 2 + 1], b3, acc[1][3], 0, 0, 0);
      const int f = 2 * u + j;
      if (f - (f / 33) * 33 == 32) FOLD(f / 33);  // uniform, 4x total
    }
    __builtin_amdgcn_s_setprio(0);
    // ledger: end of body u, allowed outstanding = A(u+1)[4] + S(u+2)[4]
    if (u < 64)       asm volatile("s_waitcnt vmcnt(8)" ::: "memory");
    else if (u == 64) asm volatile("s_waitcnt vmcnt(4)" ::: "memory");
    else              asm volatile("s_waitcnt vmcnt(0)" ::: "memory");
    __builtin_amdgcn_s_barrier();
  };

  for (int up = 0; up < 33; ++up) {
    BODY(2 * up, aC, aN);
    BODY(2 * up + 1, aN, aC);
  }

  // write per-bucket top-2 (score space: s = -2*acc)
  float4* part = (float4*)(ws + WS_PART);
  const int bucket = split * 4 + wm * 2 + kh;
#pragma unroll
  for (int nb = 0; nb < 4; ++nb) {
    const int row = zblk * 256 + wn * 128 + nb * 32 + r31;
    part[(size_t)row * 64 + bucket] =
        make_float4(-2.f * qs1[nb], (float)qi1[nb], -2.f * qs2[nb], 0.f);
  }
}

// ---------------- gather: certify / exact-rescore / flag ---------------------
__global__ __launch_bounds__(256) void gather_finalize(const float* __restrict__ Z,
                                                       const float* __restrict__ Cb,
                                                       char* __restrict__ ws,
                                                       float* __restrict__ zq,
                                                       float* __restrict__ idx_out) {
  const int w = threadIdx.x >> 6, l = threadIdx.x & 63;
  const int row = blockIdx.x * 4 + w;
  const float4 q = ((const float4*)(ws + WS_PART))[(size_t)row * 64 + l];
  float s1 = q.x;
  int i1 = (int)q.y;
#pragma unroll
  for (int off = 1; off <= 32; off <<= 1) {
    const float os = __shfl_xor(s1, off); const int oi = __shfl_xor(i1, off);
    if (os < s1 || (os == s1 && oi < i1)) { s1 = os; i1 = oi; }
  }
  const float zs = ((const float*)(ws + WS_ZSQ))[row];
  const float cmax = __int_as_float(*(const int*)(ws + WS_MAX));
  const float thr = s1 + 4.0e-3f * sqrtf(zs * cmax) + 0.05f;
  int cnt = (q.x <= thr ? 1 : 0) + (q.z <= thr ? 1 : 0);
  int hide = (q.z <= thr) ? 1 : 0;
#pragma unroll
  for (int off = 1; off <= 32; off <<= 1) {
    cnt += __shfl_xor(cnt, off);
    hide |= __shfl_xor(hide, off);
  }
  if (cnt >= 5 || hide) {
    if (l == 0) {
      const int pos = atomicAdd((int*)(ws + WS_CNT), 1);
      if (pos < Bn) ((int*)(ws + WS_WL))[pos] = row;
    }
    return;  // rescue writes this row
  }
  const float* csq = (const float*)(ws + WS_CSQ);
  const float4 z0 = *reinterpret_cast<const float4*>(Z + (size_t)row * Dn + l * 8);
  const float4 z1 = *reinterpret_cast<const float4*>(Z + (size_t)row * Dn + l * 8 + 4);
  float mycand = (q.x <= thr) ? q.x : 3e38f;
  const int myid = (int)q.y;
  float best_s = 3e38f;
  int best_i = 0x7fffffff;
  for (int it = 0; it < 4; ++it) {
    float cs_ = mycand;
    int ci_ = myid;
#pragma unroll
    for (int off = 1; off <= 32; off <<= 1) {
      const float os = __shfl_xor(cs_, off); const int oi = __shfl_xor(ci_, off);
      if (os < cs_ || (os == cs_ && oi < ci_)) { cs_ = os; ci_ = oi; }
    }
    if (cs_ > thr) break;  // wave-uniform
    if (myid == ci_) mycand = 3e38f;
    const float4 c0 = *reinterpret_cast<const float4*>(Cb + (size_t)ci_ * Dn + l * 8);
    const float4 c1 = *reinterpret_cast<const float4*>(Cb + (size_t)ci_ * Dn + l * 8 + 4);
    float pa = z0.x * c0.x + z0.y * c0.y + z0.z * c0.z + z0.w * c0.w +
               z1.x * c1.x + z1.y * c1.y + z1.z * c1.z + z1.w * c1.w;
#pragma unroll
    for (int off = 1; off <= 32; off <<= 1) pa += __shfl_xor(pa, off);
    const float se = csq[ci_] - 2.f * pa;
    if (se < best_s || (se == best_s && ci_ < best_i)) { best_s = se; best_i = ci_; }
  }
  const float4 o0 = *reinterpret_cast<const float4*>(Cb + (size_t)best_i * Dn + l * 8);
  const float4 o1 = *reinterpret_cast<const float4*>(Cb + (size_t)best_i * Dn + l * 8 + 4);
  *reinterpret_cast<float4*>(zq + (size_t)row * Dn + l * 8) = o0;
  *reinterpret_cast<float4*>(zq + (size_t)row * Dn + l * 8 + 4) = o1;
  if (l == 0) idx_out[row] = (float)best_i;
}

// ---------------- rescue1: exact fp32 scores for flagged rows ----------------
__global__ __launch_bounds__(256) void rescue1(const float* __restrict__ Z,
                                               const float* __restrict__ Cb,
                                               char* __restrict__ ws) {
  const int cntRaw = *(const int*)(ws + WS_CNT);
  const int cnt = cntRaw > Bn ? Bn : cntRaw;
  if (cnt == 0) return;
  const int tiles_r = (cnt + 63) >> 6;
  const int total = tiles_r * 128;
  const int* wl = (const int*)(ws + WS_WL);
  const float* csq = (const float*)(ws + WS_CSQ);
  float2* p2 = (float2*)(ws + WS_P2);
  __shared__ float As[32][68];
  __shared__ float Bs[32][68];
  __shared__ int wlrows[64];
  const int t = threadIdx.x;
  const int tx = t & 15, ty = t >> 4;
  const int sr = t >> 3, sc = (t & 7) * 4;
  for (int tile = blockIdx.x; tile < total; tile += gridDim.x) {
    const int tr = tile >> 7, tc = tile & 127;
    __syncthreads();
    if (t < 64) {
      const int wi = tr * 64 + t;
      wlrows[t] = wl[wi < cnt ? wi : cnt - 1];
    }
    __syncthreads();
    float acc[4][4] = {};
    for (int k0 = 0; k0 < Dn; k0 += 32) {
#pragma unroll
      for (int rr = 0; rr < 2; ++rr) {
        const int m = sr + rr * 32;
        const float4 v = *reinterpret_cast<const float4*>(Z + (size_t)wlrows[m] * Dn + k0 + sc);
        As[sc + 0][m] = v.x; As[sc + 1][m] = v.y; As[sc + 2][m] = v.z; As[sc + 3][m] = v.w;
        const float4 u = *reinterpret_cast<const float4*>(Cb + (size_t)(tc * 64 + m) * Dn + k0 + sc);
        Bs[sc + 0][m] = u.x; Bs[sc + 1][m] = u.y; Bs[sc + 2][m] = u.z; Bs[sc + 3][m] = u.w;
      }
      __syncthreads();
#pragma unroll
      for (int k = 0; k < 32; ++k) {
        const float4 a = *reinterpret_cast<const float4*>(&As[k][ty * 4]);
        const float4 b = *reinterpret_cast<const float4*>(&Bs[k][tx * 4]);
        acc[0][0] += a.x * b.x; acc[0][1] += a.x * b.y; acc[0][2] += a.x * b.z; acc[0][3] += a.x * b.w;
        acc[1][0] += a.y * b.x; acc[1][1] += a.y * b.y; acc[1][2] += a.y * b.z; acc[1][3] += a.y * b.w;
        acc[2][0] += a.z * b.x; acc[2][1] += a.z * b.y; acc[2][2] += a.z * b.z; acc[2][3] += a.z * b.w;
        acc[3][0] += a.w * b.x; acc[3][1] += a.w * b.y; acc[3][2] += a.w * b.z; acc[3][3] += a.w * b.w;
      }
      __syncthreads();
    }
#pragma unroll
    for (int i = 0; i < 4; ++i) {
      float bsv = 3e38f;
      int bi = 0;
#pragma unroll
      for (int j = 0; j < 4; ++j) {
        const int n = tc * 64 + tx * 4 + j;
        const float s = csq[n] - 2.f * acc[i][j];
        if (s < bsv || (s == bsv && n < bi)) { bsv = s; bi = n; }
      }
#pragma unroll
      for (int off = 1; off <= 8; off <<= 1) {
        const float os = __shfl_xor(bsv, off); const int oi = __shfl_xor(bi, off);
        if (os < bsv || (os == bsv && oi < bi)) { bsv = os; bi = oi; }
      }
      if (tx == 0) p2[(size_t)(tr * 64 + ty * 4 + i) * 128 + tc] = make_float2(bsv, (float)bi);
    }
  }
}

// ---------------- rescue2: combine col-tile minima + write -------------------
__global__ __launch_bounds__(64) void rescue2(const float* __restrict__ Cb,
                                              char* __restrict__ ws,
                                              float* __restrict__ zq,
                                              float* __restrict__ idx_out) {
  const int cntRaw = *(const int*)(ws + WS_CNT);
  const int cnt = cntRaw > Bn ? Bn : cntRaw;
  const int* wl = (const int*)(ws + WS_WL);
  const float2* p2 = (const float2*)(ws + WS_P2);
  const int l = threadIdx.x;
  for (int rr = blockIdx.x; rr < cnt; rr += gridDim.x) {
    const int row = wl[rr];
    const float2 e1 = p2[(size_t)rr * 128 + l];
    const float2 e2 = p2[(size_t)rr * 128 + 64 + l];
    float bs_ = e1.x;
    int bi_ = (int)e1.y;
    if (e2.x < bs_ || (e2.x == bs_ && (int)e2.y < bi_)) { bs_ = e2.x; bi_ = (int)e2.y; }
#pragma unroll
    for (int off = 1; off <= 32; off <<= 1) {
      const float os = __shfl_xor(bs_, off); const int oi = __shfl_xor(bi_, off);
      if (os < bs_ || (os == bs_ && oi < bi_)) { bs_ = os; bi_ = oi; }
    }
    const float4 c0 = *reinterpret_cast<const float4*>(Cb + (size_t)bi_ * Dn + l * 8);
    const float4 c1 = *reinterpret_cast<const float4*>(Cb + (size_t)bi_ * Dn + l * 8 + 4);
    *reinterpret_cast<float4*>(zq + (size_t)row * Dn + l * 8) = c0;
    *reinterpret_cast<float4*>(zq + (size_t)row * Dn + l * 8 + 4) = c1;
    if (l == 0) idx_out[row] = (float)bi_;
  }
}

extern "C" void kernel_launch(void* const* d_in, const int* in_sizes, int n_in,
                              void* d_out, int out_size, void* d_ws, size_t ws_size,
                              hipStream_t stream) {
  const float* Z = (const float*)d_in[0];  // [B, D]
  const float* C = (const float*)d_in[1];  // [K, D]
  float* out = (float*)d_out;              // [B*D] z_q then [B] indices
  char* ws = (char*)d_ws;                  // ~27.7MB

  prep_sums<<<4096, 256, 0, stream>>>(Z, C, ws);
  prep_img<<<640, 256, 0, stream>>>(Z, C, ws);
  vq_pass1<<<512, 256, 0, stream>>>(ws);
  gather_finalize<<<2048, 256, 0, stream>>>(Z, C, ws, out, out + (size_t)Bn * Dn);
  rescue1<<<512, 256, 0, stream>>>(Z, C, ws);
  rescue2<<<256, 64, 0, stream>>>(C, ws, out, out + (size_t)Bn * Dn);
}

// Round 9
// 272.741 us; speedup vs baseline: 2.2704x; 2.2704x over previous
//
#include <hip/hip_runtime.h>

// VQ nearest-neighbor, two-pass, swapped-operand MFMA (round 9).
//  pass1: mfma(A=codebook_h, B=z_h): lane holds 32 candidates for its own z-row
//         in acc regs; per-panel ext MFMA adds -csq/2 (B = const {1,1,0..});
//         in-lane top-2 fold in acc space; fully-static inner loop (unroll 32),
//         4-buffer LDS rotation, prefetch distance 2, counted vmcnt.
//  gather: certify winner via sound margin / exact-rescore visible / flag row;
//  rescue: exact fp32 re-scan of flagged rows.
// score(k) = csq[k] - 2*z.c_k = -2*acc  (argmin score == argmax acc)

constexpr int Bn = 8192;
constexpr int Kn = 8192;
constexpr int Dn = 512;

using half8  = __attribute__((ext_vector_type(8)))  _Float16;
using f32x16 = __attribute__((ext_vector_type(16))) float;

// workspace layout (bytes), ~26.3MB
#define WS_CSQ  0u
#define WS_ZSQ  (32u*1024u)
#define WS_MAX  (64u*1024u)
#define WS_CNT  (64u*1024u + 64u)
#define WS_WL   (96u*1024u)
#define WS_PART (1u*1024u*1024u)   // float4 partials[8192][64] = 8MB
#define WS_P2   WS_PART            // rescue p2 aliases PART (dead after gather)
#define WS_CIMG (10u*1024u*1024u)  // codebook h image: 64 blk x 32 kt x 4KB = 8MB
#define WS_ZIMG (18u*1024u*1024u)  // z h image:        32 blk x 32 kt x 8KB = 8MB
#define WS_CEXT (26u*1024u*1024u)  // ext frags: 64 blk x 4 grp x 1KB = 256KB

typedef __attribute__((address_space(3))) void       as3_void;
typedef const __attribute__((address_space(1))) void as1_cvoid;

#define MFMA16 __builtin_amdgcn_mfma_f32_32x32x16_f16

// Images are fragment-contiguous: tile = blk*32+kt (C: 4KB, Z: 8KB); within a
// tile, 1KB frag per 32-row group; chunk16B[kh*32+rr] = row grp*32+rr, k-half kh.
// CEXT frag (per colblk,grp): chunk[rr] (rr<32) = {-csq/2 hi, lo, 0...}; rr>=32 zeros.

// ---------------- prep_sums: row sumsq (exact fp32) + cmax -------------------
__global__ __launch_bounds__(256) void prep_sums(const float* __restrict__ Z,
                                                 const float* __restrict__ Cb,
                                                 char* __restrict__ ws) {
  const int w = threadIdx.x >> 6, lane = threadIdx.x & 63;
  const int rid = blockIdx.x * 4 + w;  // 0..16383
  if (blockIdx.x == 0 && threadIdx.x == 0) *(int*)(ws + WS_CNT) = 0;
  const bool isZ = rid < Bn;
  const int r = isZ ? rid : rid - Bn;
  const float* src = (isZ ? Z : Cb) + (size_t)r * Dn + lane * 8;
  const float4 v0 = *reinterpret_cast<const float4*>(src);
  const float4 v1 = *reinterpret_cast<const float4*>(src + 4);
  float ss = v0.x * v0.x + v0.y * v0.y + v0.z * v0.z + v0.w * v0.w +
             v1.x * v1.x + v1.y * v1.y + v1.z * v1.z + v1.w * v1.w;
#pragma unroll
  for (int off = 32; off; off >>= 1) ss += __shfl_xor(ss, off);
  if (lane == 0) {
    if (isZ) ((float*)(ws + WS_ZSQ))[r] = ss;
    else {
      ((float*)(ws + WS_CSQ))[r] = ss;
      atomicMax((int*)(ws + WS_MAX), __float_as_int(ss));  // ss>0: int order == float order
    }
  }
}

// ---------------- prep_img: wave-per-fragment, coalesced writes --------------
__global__ __launch_bounds__(256) void prep_img(const float* __restrict__ Z,
                                                const float* __restrict__ Cb,
                                                char* __restrict__ ws) {
  const int w = threadIdx.x >> 6, lane = threadIdx.x & 63;
  const int wid = blockIdx.x * 4 + w;  // 0..2303
  char* CI = ws + WS_CIMG;
  char* ZI = ws + WS_ZIMG;
  char* CE = ws + WS_CEXT;
  if (wid < 2048) {
    const bool isC = wid < 1024;
    const int f = isC ? wid : wid - 1024;
    const int koct = f & 3;
    const int grp = isC ? ((f >> 2) & 3) : ((f >> 2) & 7);
    const int blk = isC ? (f >> 4) : (f >> 5);
    const int rowbase = (isC ? blk * 128 : blk * 256) + grp * 32;
    const float* src = isC ? Cb : Z;
    char* img = isC ? CI : ZI;
    const int fr = isC ? 256 : 512;
    const int ktsel = lane & 1, rr = lane >> 1;
    const float* rowp = src + (size_t)(rowbase + rr) * Dn;
#pragma unroll
    for (int kp = 0; kp < 4; ++kp) {
      const int kt = koct * 8 + kp * 2 + ktsel;
      const float4 v0 = *reinterpret_cast<const float4*>(rowp + kt * 16);
      const float4 v1 = *reinterpret_cast<const float4*>(rowp + kt * 16 + 4);
      const float4 v2 = *reinterpret_cast<const float4*>(rowp + kt * 16 + 8);
      const float4 v3 = *reinterpret_cast<const float4*>(rowp + kt * 16 + 12);
      const float fl[16] = {v0.x, v0.y, v0.z, v0.w, v1.x, v1.y, v1.z, v1.w,
                            v2.x, v2.y, v2.z, v2.w, v3.x, v3.y, v3.z, v3.w};
      _Float16 h[16];
#pragma unroll
      for (int j = 0; j < 16; ++j) h[j] = (_Float16)fl[j];
      const half8 lo8 = {h[0], h[1], h[2], h[3], h[4], h[5], h[6], h[7]};
      const half8 hi8 = {h[8], h[9], h[10], h[11], h[12], h[13], h[14], h[15]};
      char* fb = img + ((size_t)(blk * 32 + kt) * fr + grp * 64) * 16;
      *reinterpret_cast<half8*>(fb + rr * 16) = lo8;        // kh=0 chunk
      *reinterpret_cast<half8*>(fb + 512 + rr * 16) = hi8;  // kh=1 chunk
    }
  } else {  // C ext frags (csq baked): wid 2048..2303 -> (blk 0..63, grp 0..3)
    const int e = wid - 2048;
    const int grp = e & 3, blk = e >> 2;
    half8 ev = {};
    if (lane < 32) {
      const float ss = ((const float*)(ws + WS_CSQ))[blk * 128 + grp * 32 + lane];
      const _Float16 hi = (_Float16)(-0.5f * ss);
      ev[0] = hi;
      ev[1] = (_Float16)(-0.5f * ss - (float)hi);
    }
    char* fb = CE + (size_t)(blk * 4 + grp) * 1024;
    *reinterpret_cast<half8*>(fb + lane * 16) = ev;
  }
}

// ---------------- pass1 ------------------------------------------------------
// 512 blocks (2/CU), 256 thr (4 waves: wm = codebook half, wn = z half).
// XCD swizzle: xcd = bid&7 hosts zblks 4*xcd..+3 (1MB z slice, L2-resident).
// Block: z 256 rows x codebook 512 cols (4 panels x 128); 32 kt per panel.
__global__ __launch_bounds__(256, 2) void vq_pass1(char* __restrict__ ws) {
  __shared__ uint4 lds4[4096];  // 64KB: 4 rotating 16KB z buffers
  char* lds = (char*)lds4;
  const int t = threadIdx.x, lane = t & 63, w = t >> 6;
  const int wm = w >> 1, wn = w & 1;
  const int bid = blockIdx.x;
  const int zblk = (bid & 7) * 4 + ((bid >> 3) & 3);
  const int split = bid >> 5;
  const int r31 = lane & 31, kh = lane >> 5;
  const size_t l16 = (size_t)lane * 16;

  const char* zsrcT = ws + WS_ZIMG + (size_t)zblk * 262144 + (size_t)w * 2048 + l16;
  char* const ldsW = lds + w * 2048;
  const char* APt = ws + WS_CIMG + (size_t)(split * 4) * 131072 + wm * 2048 + l16;
  const char* EbT = ws + WS_CEXT + (size_t)(split * 4) * 4096 + wm * 2048 + l16;
  const char* ldsRd = lds + wn * 4096 + kh * 512 + r31 * 16;

  half8 aset[4][2], aE[2];
  half8 bext = {};
  if (kh == 0) { bext[0] = (_Float16)1.f; bext[1] = (_Float16)1.f; }

  float qm1[4], qm2[4];
  int qi[4];
#pragma unroll
  for (int nb = 0; nb < 4; ++nb) { qm1[nb] = -3e38f; qm2[nb] = -3e38f; qi[nb] = 0x7fffffff; }
  f32x16 acc[2][4] = {};

#define GLDS(S, D) __builtin_amdgcn_global_load_lds((as1_cvoid*)(S), (as3_void*)(D), 16, 0, 0)

  // prologue: S(0), A(0), S(1), A(1), ext(p0).  younger-than-S(0) = 8.
  GLDS(zsrcT, ldsW); GLDS(zsrcT + 1024, ldsW + 1024);
  aset[0][0] = *reinterpret_cast<const half8*>(APt);
  aset[0][1] = *reinterpret_cast<const half8*>(APt + 1024);
  GLDS(zsrcT + 8192, ldsW + 16384); GLDS(zsrcT + 8192 + 1024, ldsW + 16384 + 1024);
  aset[1][0] = *reinterpret_cast<const half8*>(APt + 4096);
  aset[1][1] = *reinterpret_cast<const half8*>(APt + 4096 + 1024);
  aE[0] = *reinterpret_cast<const half8*>(EbT);
  aE[1] = *reinterpret_cast<const half8*>(EbT + 1024);
  asm volatile("s_waitcnt vmcnt(8)" ::: "memory");
  __builtin_amdgcn_s_barrier();

  for (int p = 0; p < 4; ++p) {
#pragma unroll
    for (int kt = 0; kt < 32; ++kt) {
      // A prefetch (kt+2), static reg-set (kt+2)&3
      {
        const char* An = (kt < 30) ? APt + (kt + 2) * 4096
                                   : APt + 131072 + (kt - 30) * 4096;
        aset[(kt + 2) & 3][0] = *reinterpret_cast<const half8*>(An);
        aset[(kt + 2) & 3][1] = *reinterpret_cast<const half8*>(An + 1024);
      }
      // stage z tile (kt+2)&31 into buffer (kt+2)&3
      {
        const char* zs = zsrcT + ((kt + 2) & 31) * 8192;
        char* zd = ldsW + ((kt + 2) & 3) * 16384;
        GLDS(zs, zd); GLDS(zs + 1024, zd + 1024);
      }
      // compute on buffer kt&3 with reg-set kt&3 (LDS offsets all immediate)
      {
        const char* bb = ldsRd + (kt & 3) * 16384;
        const half8 b0 = *reinterpret_cast<const half8*>(bb);
        const half8 b1 = *reinterpret_cast<const half8*>(bb + 1024);
        const half8 b2 = *reinterpret_cast<const half8*>(bb + 2048);
        const half8 b3 = *reinterpret_cast<const half8*>(bb + 3072);
        const half8 a0 = aset[kt & 3][0];
        const half8 a1 = aset[kt & 3][1];
        acc[0][0] = MFMA16(a0, b0, acc[0][0], 0, 0, 0);
        acc[0][1] = MFMA16(a0, b1, acc[0][1], 0, 0, 0);
        acc[0][2] = MFMA16(a0, b2, acc[0][2], 0, 0, 0);
        acc[0][3] = MFMA16(a0, b3, acc[0][3], 0, 0, 0);
        acc[1][0] = MFMA16(a1, b0, acc[1][0], 0, 0, 0);
        acc[1][1] = MFMA16(a1, b1, acc[1][1], 0, 0, 0);
        acc[1][2] = MFMA16(a1, b2, acc[1][2], 0, 0, 0);
        acc[1][3] = MFMA16(a1, b3, acc[1][3], 0, 0, 0);
      }
      // ledger: S(kt+1) must land; younger = A(kt+2)+S(kt+2) (+ext at kt==0)
      if (kt == 0) asm volatile("s_waitcnt vmcnt(6)" ::: "memory");
      else         asm volatile("s_waitcnt vmcnt(4)" ::: "memory");
      __builtin_amdgcn_s_barrier();
    }
    // ---- ext step: add -csq/2 (B operand constant, no load) ----
#pragma unroll
    for (int nb = 0; nb < 4; ++nb) {
      acc[0][nb] = MFMA16(aE[0], bext, acc[0][nb], 0, 0, 0);
      acc[1][nb] = MFMA16(aE[1], bext, acc[1][nb], 0, 0, 0);
    }
    // ---- in-lane top-2 fold (acc space; score = -2*a, so argmax a) ----
    {
      const int cb = split * 512 + p * 128 + wm * 64 + 4 * kh;
#pragma unroll
      for (int nb = 0; nb < 4; ++nb) {
        float m1 = qm1[nb], m2 = qm2[nb];
        int i1 = qi[nb];
#pragma unroll
        for (int ms = 0; ms < 2; ++ms)
#pragma unroll
          for (int r = 0; r < 16; ++r) {
            const float a = acc[ms][nb][r];
            const int ci = cb + ms * 32 + (r & 3) + 8 * (r >> 2);
            const bool gt = (a > m1) || (a == m1 && ci < i1);
            const float nm2 = gt ? m1 : fmaxf(m2, a);
            m1 = gt ? a : m1;
            i1 = gt ? ci : i1;
            m2 = nm2;
          }
        qm1[nb] = m1; qm2[nb] = m2; qi[nb] = i1;
        acc[0][nb] = (f32x16)0.f;
        acc[1][nb] = (f32x16)0.f;
      }
    }
    APt += 131072;
    if (p < 3) {  // ext frags for next panel (issued at panel start)
      aE[0] = *reinterpret_cast<const half8*>(EbT + (p + 1) * 4096);
      aE[1] = *reinterpret_cast<const half8*>(EbT + (p + 1) * 4096 + 1024);
    }
  }
  asm volatile("s_waitcnt vmcnt(0)" ::: "memory");

  // write per-bucket top-2 (score space: s = -2*m)
  float4* part = (float4*)(ws + WS_PART);
  const int bucket = split * 4 + wm * 2 + kh;
#pragma unroll
  for (int nb = 0; nb < 4; ++nb) {
    const int row = zblk * 256 + wn * 128 + nb * 32 + r31;
    part[(size_t)row * 64 + bucket] =
        make_float4(-2.f * qm1[nb], (float)qi[nb], -2.f * qm2[nb], 0.f);
  }
#undef GLDS
}

// ---------------- gather: certify / exact-rescore / flag ---------------------
__global__ __launch_bounds__(256) void gather_finalize(const float* __restrict__ Z,
                                                       const float* __restrict__ Cb,
                                                       char* __restrict__ ws,
                                                       float* __restrict__ zq,
                                                       float* __restrict__ idx_out) {
  const int w = threadIdx.x >> 6, l = threadIdx.x & 63;
  const int row = blockIdx.x * 4 + w;
  const float4 q = ((const float4*)(ws + WS_PART))[(size_t)row * 64 + l];
  float s1 = q.x;
  int i1 = (int)q.y;
#pragma unroll
  for (int off = 1; off <= 32; off <<= 1) {
    const float os = __shfl_xor(s1, off); const int oi = __shfl_xor(i1, off);
    if (os < s1 || (os == s1 && oi < i1)) { s1 = os; i1 = oi; }
  }
  const float zs = ((const float*)(ws + WS_ZSQ))[row];
  const float cmax = __int_as_float(*(const int*)(ws + WS_MAX));
  const float thr = s1 + 4.0e-3f * sqrtf(zs * cmax) + 0.05f;
  int cnt = (q.x <= thr ? 1 : 0) + (q.z <= thr ? 1 : 0);
  int hide = (q.z <= thr) ? 1 : 0;
#pragma unroll
  for (int off = 1; off <= 32; off <<= 1) {
    cnt += __shfl_xor(cnt, off);
    hide |= __shfl_xor(hide, off);
  }
  if (cnt >= 5 || hide) {
    if (l == 0) {
      const int pos = atomicAdd((int*)(ws + WS_CNT), 1);
      if (pos < Bn) ((int*)(ws + WS_WL))[pos] = row;
    }
    return;  // rescue writes this row
  }
  const float* csq = (const float*)(ws + WS_CSQ);
  const float4 z0 = *reinterpret_cast<const float4*>(Z + (size_t)row * Dn + l * 8);
  const float4 z1 = *reinterpret_cast<const float4*>(Z + (size_t)row * Dn + l * 8 + 4);
  float mycand = (q.x <= thr) ? q.x : 3e38f;
  const int myid = (int)q.y;
  float best_s = 3e38f;
  int best_i = 0x7fffffff;
  for (int it = 0; it < 4; ++it) {
    float cs_ = mycand;
    int ci_ = myid;
#pragma unroll
    for (int off = 1; off <= 32; off <<= 1) {
      const float os = __shfl_xor(cs_, off); const int oi = __shfl_xor(ci_, off);
      if (os < cs_ || (os == cs_ && oi < ci_)) { cs_ = os; ci_ = oi; }
    }
    if (cs_ > thr) break;  // wave-uniform
    if (myid == ci_) mycand = 3e38f;
    const float4 c0 = *reinterpret_cast<const float4*>(Cb + (size_t)ci_ * Dn + l * 8);
    const float4 c1 = *reinterpret_cast<const float4*>(Cb + (size_t)ci_ * Dn + l * 8 + 4);
    float pa = z0.x * c0.x + z0.y * c0.y + z0.z * c0.z + z0.w * c0.w +
               z1.x * c1.x + z1.y * c1.y + z1.z * c1.z + z1.w * c1.w;
#pragma unroll
    for (int off = 1; off <= 32; off <<= 1) pa += __shfl_xor(pa, off);
    const float se = csq[ci_] - 2.f * pa;
    if (se < best_s || (se == best_s && ci_ < best_i)) { best_s = se; best_i = ci_; }
  }
  const float4 o0 = *reinterpret_cast<const float4*>(Cb + (size_t)best_i * Dn + l * 8);
  const float4 o1 = *reinterpret_cast<const float4*>(Cb + (size_t)best_i * Dn + l * 8 + 4);
  *reinterpret_cast<float4*>(zq + (size_t)row * Dn + l * 8) = o0;
  *reinterpret_cast<float4*>(zq + (size_t)row * Dn + l * 8 + 4) = o1;
  if (l == 0) idx_out[row] = (float)best_i;
}

// ---------------- rescue1: exact fp32 scores for flagged rows ----------------
__global__ __launch_bounds__(256) void rescue1(const float* __restrict__ Z,
                                               const float* __restrict__ Cb,
                                               char* __restrict__ ws) {
  const int cntRaw = *(const int*)(ws + WS_CNT);
  const int cnt = cntRaw > Bn ? Bn : cntRaw;
  if (cnt == 0) return;
  const int tiles_r = (cnt + 63) >> 6;
  const int total = tiles_r * 128;
  const int* wl = (const int*)(ws + WS_WL);
  const float* csq = (const float*)(ws + WS_CSQ);
  float2* p2 = (float2*)(ws + WS_P2);
  __shared__ float As[32][68];
  __shared__ float Bs[32][68];
  __shared__ int wlrows[64];
  const int t = threadIdx.x;
  const int tx = t & 15, ty = t >> 4;
  const int sr = t >> 3, sc = (t & 7) * 4;
  for (int tile = blockIdx.x; tile < total; tile += gridDim.x) {
    const int tr = tile >> 7, tc = tile & 127;
    __syncthreads();
    if (t < 64) {
      const int wi = tr * 64 + t;
      wlrows[t] = wl[wi < cnt ? wi : cnt - 1];
    }
    __syncthreads();
    float acc[4][4] = {};
    for (int k0 = 0; k0 < Dn; k0 += 32) {
#pragma unroll
      for (int rr = 0; rr < 2; ++rr) {
        const int m = sr + rr * 32;
        const float4 v = *reinterpret_cast<const float4*>(Z + (size_t)wlrows[m] * Dn + k0 + sc);
        As[sc + 0][m] = v.x; As[sc + 1][m] = v.y; As[sc + 2][m] = v.z; As[sc + 3][m] = v.w;
        const float4 u = *reinterpret_cast<const float4*>(Cb + (size_t)(tc * 64 + m) * Dn + k0 + sc);
        Bs[sc + 0][m] = u.x; Bs[sc + 1][m] = u.y; Bs[sc + 2][m] = u.z; Bs[sc + 3][m] = u.w;
      }
      __syncthreads();
#pragma unroll
      for (int k = 0; k < 32; ++k) {
        const float4 a = *reinterpret_cast<const float4*>(&As[k][ty * 4]);
        const float4 b = *reinterpret_cast<const float4*>(&Bs[k][tx * 4]);
        acc[0][0] += a.x * b.x; acc[0][1] += a.x * b.y; acc[0][2] += a.x * b.z; acc[0][3] += a.x * b.w;
        acc[1][0] += a.y * b.x; acc[1][1] += a.y * b.y; acc[1][2] += a.y * b.z; acc[1][3] += a.y * b.w;
        acc[2][0] += a.z * b.x; acc[2][1] += a.z * b.y; acc[2][2] += a.z * b.z; acc[2][3] += a.z * b.w;
        acc[3][0] += a.w * b.x; acc[3][1] += a.w * b.y; acc[3][2] += a.w * b.z; acc[3][3] += a.w * b.w;
      }
      __syncthreads();
    }
#pragma unroll
    for (int i = 0; i < 4; ++i) {
      float bsv = 3e38f;
      int bi = 0;
#pragma unroll
      for (int j = 0; j < 4; ++j) {
        const int n = tc * 64 + tx * 4 + j;
        const float s = csq[n] - 2.f * acc[i][j];
        if (s < bsv || (s == bsv && n < bi)) { bsv = s; bi = n; }
      }
#pragma unroll
      for (int off = 1; off <= 8; off <<= 1) {
        const float os = __shfl_xor(bsv, off); const int oi = __shfl_xor(bi, off);
        if (os < bsv || (os == bsv && oi < bi)) { bsv = os; bi = oi; }
      }
      if (tx == 0) p2[(size_t)(tr * 64 + ty * 4 + i) * 128 + tc] = make_float2(bsv, (float)bi);
    }
  }
}

// ---------------- rescue2: combine col-tile minima + write -------------------
__global__ __launch_bounds__(64) void rescue2(const float* __restrict__ Cb,
                                              char* __restrict__ ws,
                                              float* __restrict__ zq,
                                              float* __restrict__ idx_out) {
  const int cntRaw = *(const int*)(ws + WS_CNT);
  const int cnt = cntRaw > Bn ? Bn : cntRaw;
  const int* wl = (const int*)(ws + WS_WL);
  const float2* p2 = (const float2*)(ws + WS_P2);
  const int l = threadIdx.x;
  for (int rr = blockIdx.x; rr < cnt; rr += gridDim.x) {
    const int row = wl[rr];
    const float2 e1 = p2[(size_t)rr * 128 + l];
    const float2 e2 = p2[(size_t)rr * 128 + 64 + l];
    float bs_ = e1.x;
    int bi_ = (int)e1.y;
    if (e2.x < bs_ || (e2.x == bs_ && (int)e2.y < bi_)) { bs_ = e2.x; bi_ = (int)e2.y; }
#pragma unroll
    for (int off = 1; off <= 32; off <<= 1) {
      const float os = __shfl_xor(bs_, off); const int oi = __shfl_xor(bi_, off);
      if (os < bs_ || (os == bs_ && oi < bi_)) { bs_ = os; bi_ = oi; }
    }
    const float4 c0 = *reinterpret_cast<const float4*>(Cb + (size_t)bi_ * Dn + l * 8);
    const float4 c1 = *reinterpret_cast<const float4*>(Cb + (size_t)bi_ * Dn + l * 8 + 4);
    *reinterpret_cast<float4*>(zq + (size_t)row * Dn + l * 8) = c0;
    *reinterpret_cast<float4*>(zq + (size_t)row * Dn + l * 8 + 4) = c1;
    if (l == 0) idx_out[row] = (float)bi_;
  }
}

extern "C" void kernel_launch(void* const* d_in, const int* in_sizes, int n_in,
                              void* d_out, int out_size, void* d_ws, size_t ws_size,
                              hipStream_t stream) {
  const float* Z = (const float*)d_in[0];  // [B, D]
  const float* C = (const float*)d_in[1];  // [K, D]
  float* out = (float*)d_out;              // [B*D] z_q then [B] indices
  char* ws = (char*)d_ws;                  // ~26.3MB

  prep_sums<<<4096, 256, 0, stream>>>(Z, C, ws);
  prep_img<<<576, 256, 0, stream>>>(Z, C, ws);
  vq_pass1<<<512, 256, 0, stream>>>(ws);
  gather_finalize<<<2048, 256, 0, stream>>>(Z, C, ws, out, out + (size_t)Bn * Dn);
  rescue1<<<512, 256, 0, stream>>>(Z, C, ws);
  rescue2<<<256, 64, 0, stream>>>(C, ws, out, out + (size_t)Bn * Dn);
}